// Round 1
// baseline (592.405 us; speedup 1.0000x reference)
//
#include <hip/hip_runtime.h>
#include <hip/hip_bf16.h>

// SAGEConv mean-aggr: out_i = mean_{j->i} x_j @ W_l^T + b_l + x_i @ W_r^T
// Key restructuring: project FIRST (h_l = x@W_l^T, h_r = x@W_r^T, each N x 5),
// then scatter 5 floats/edge instead of 128. Irregular traffic drops from
// ~820 MB to ~32 MB of gathers out of a 3.2 MB L2-resident table.

#define N_NODES 100000
#define N_EDGES 1600000
#define D_IN 128
#define D_OUT 5

// hl padded to 8 floats/node for aligned float4 gather in the edge kernel.
#define HL_STRIDE 8

// ---------------------------------------------------------------------------
// Kernel 1: projection. 16 lanes per node; lane k loads dims [8k, 8k+8) of the
// node row (two float4 = 32 B/lane, 512 B contiguous per 16-lane group), forms
// partial dots for all 10 outputs (5 for W_l, 5 for W_r), butterfly-reduces
// within the 16-lane group, lane 0 writes the 10 results.
// ---------------------------------------------------------------------------
__global__ __launch_bounds__(256) void proj_kernel(
    const float* __restrict__ x,
    const float* __restrict__ Wl,
    const float* __restrict__ Wr,
    float* __restrict__ hl,   // [N_NODES][HL_STRIDE], first 5 valid
    float* __restrict__ hr)   // [N_NODES][5]
{
    int node = (blockIdx.x * 256 + threadIdx.x) >> 4;
    int k    = threadIdx.x & 15;
    if (node >= N_NODES) return;

    const float4* xr = (const float4*)(x + (size_t)node * D_IN + k * 8);
    float4 x0 = xr[0];
    float4 x1 = xr[1];

    float s[10];
#pragma unroll
    for (int o = 0; o < 10; ++o) {
        const float* w = (o < 5 ? Wl + o * D_IN : Wr + (o - 5) * D_IN) + k * 8;
        float4 w0 = ((const float4*)w)[0];
        float4 w1 = ((const float4*)w)[1];
        s[o] = x0.x * w0.x + x0.y * w0.y + x0.z * w0.z + x0.w * w0.w
             + x1.x * w1.x + x1.y * w1.y + x1.z * w1.z + x1.w * w1.w;
    }

    // butterfly reduce within the 16-lane group (xor masks < 16 stay in-group)
#pragma unroll
    for (int o = 0; o < 10; ++o) {
        s[o] += __shfl_xor(s[o], 8, 64);
        s[o] += __shfl_xor(s[o], 4, 64);
        s[o] += __shfl_xor(s[o], 2, 64);
        s[o] += __shfl_xor(s[o], 1, 64);
    }

    if (k == 0) {
        float* pl = hl + (size_t)node * HL_STRIDE;
        pl[0] = s[0]; pl[1] = s[1]; pl[2] = s[2]; pl[3] = s[3]; pl[4] = s[4];
        float* pr = hr + (size_t)node * 5;
        pr[0] = s[5]; pr[1] = s[6]; pr[2] = s[7]; pr[3] = s[8]; pr[4] = s[9];
    }
}

// ---------------------------------------------------------------------------
// Kernel 2: edge scatter. One thread per edge: gather h_l[src] (20 B from the
// L2-resident padded table), 6 fire-and-forget fp32 atomics into agg[dst][6]
// (5 channels + degree count in slot 5).
// ---------------------------------------------------------------------------
__global__ __launch_bounds__(256) void edge_kernel(
    const int* __restrict__ ei,     // [2][N_EDGES], row0 = src, row1 = dst
    const float* __restrict__ hl,
    float* __restrict__ agg)        // [N_NODES][6], zero-initialized
{
    int e = blockIdx.x * 256 + threadIdx.x;
    if (e >= N_EDGES) return;

    int src = ei[e];
    int dst = ei[N_EDGES + e];

    const float* p = hl + (size_t)src * HL_STRIDE;
    float4 v  = ((const float4*)p)[0];
    float  v4 = p[4];

    float* a = agg + (size_t)dst * 6;
    unsafeAtomicAdd(a + 0, v.x);
    unsafeAtomicAdd(a + 1, v.y);
    unsafeAtomicAdd(a + 2, v.z);
    unsafeAtomicAdd(a + 3, v.w);
    unsafeAtomicAdd(a + 4, v4);
    unsafeAtomicAdd(a + 5, 1.0f);
}

// ---------------------------------------------------------------------------
// Kernel 3: finalize. out[i][o] = agg[i][o] / max(deg,1) + b_l[o] + hr[i][o]
// ---------------------------------------------------------------------------
__global__ __launch_bounds__(256) void final_kernel(
    const float* __restrict__ agg,
    const float* __restrict__ hr,
    const float* __restrict__ b,
    float* __restrict__ out)
{
    int i = blockIdx.x * 256 + threadIdx.x;
    if (i >= N_NODES) return;

    const float* a = agg + (size_t)i * 6;
    float deg = a[5];
    float rec = 1.0f / fmaxf(deg, 1.0f);

    const float* h = hr + (size_t)i * 5;
    float* o = out + (size_t)i * 5;
#pragma unroll
    for (int c = 0; c < 5; ++c)
        o[c] = a[c] * rec + b[c] + h[c];
}

extern "C" void kernel_launch(void* const* d_in, const int* in_sizes, int n_in,
                              void* d_out, int out_size, void* d_ws, size_t ws_size,
                              hipStream_t stream) {
    const float* x    = (const float*)d_in[0];
    const int*   ei   = (const int*)d_in[1];     // int32 per harness convention
    const float* Wl   = (const float*)d_in[2];
    const float* bl   = (const float*)d_in[3];
    const float* Wr   = (const float*)d_in[4];
    float*       out  = (float*)d_out;

    // workspace layout (all 16B-aligned offsets)
    float* hl  = (float*)d_ws;                            // 100000*8 = 800000 f
    float* hr  = hl + (size_t)N_NODES * HL_STRIDE;        // 500000 f
    float* agg = hr + (size_t)N_NODES * 5;                // 600000 f

    // zero the accumulator (ws is re-poisoned to 0xAA before every launch)
    hipMemsetAsync(agg, 0, (size_t)N_NODES * 6 * sizeof(float), stream);

    {   // projection: 16 threads/node, 256/block -> 16 nodes/block
        int blocks = (N_NODES * 16 + 255) / 256;          // 6250
        proj_kernel<<<blocks, 256, 0, stream>>>(x, Wl, Wr, hl, hr);
    }
    {   // edge scatter: 1 thread/edge
        int blocks = (N_EDGES + 255) / 256;               // 6250
        edge_kernel<<<blocks, 256, 0, stream>>>(ei, hl, agg);
    }
    {   // finalize
        int blocks = (N_NODES + 255) / 256;               // 391
        final_kernel<<<blocks, 256, 0, stream>>>(agg, hr, bl, out);
    }
}

// Round 2
// 468.552 us; speedup vs baseline: 1.2643x; 1.2643x over previous
//
#include <hip/hip_runtime.h>
#include <hip/hip_bf16.h>

// SAGEConv mean-aggr: out_i = mean_{j->i} x_j @ W_l^T + b_l + x_i @ W_r^T
//
// R1 lesson (rocprof): device-scope fp32 atomics write through L2 — 9.6M
// atomics x 32B = 300 MB WRITE_SIZE, 481 us at ~20 G atomics/s. So R2
// eliminates ALL global atomics:
//   1. proj: h_l = x@W_l^T (padded stride 8), h_r = x@W_r^T   [N x 5 each]
//   2. bucket: nodes split into 49 buckets of 2048 (48 KB LDS acc),
//      edges into 8 chunks; each of 392 blocks streams its chunk's dst
//      array, LDS-atomic-accumulates matching edges, flushes the whole
//      bucket to partials[chunk] with coalesced float4 stores.
//   3. final: sum 8 partials, divide by degree, + b_l + h_r.

#define N_NODES 100000
#define N_EDGES 1600000
#define D_IN 128
#define D_OUT 5

#define HL_STRIDE 8

#define B_NODES 2048                      // nodes per bucket
#define N_BUCKETS 49                      // ceil(100000/2048)
#define NODES_PAD (N_BUCKETS * B_NODES)   // 100352
#define N_CHUNKS 8
#define CHUNK_E (N_EDGES / N_CHUNKS)      // 200000

// ---------------------------------------------------------------------------
// Kernel 1: projection. 16 lanes/node, lane k covers dims [8k,8k+8).
// ---------------------------------------------------------------------------
__global__ __launch_bounds__(256) void proj_kernel(
    const float* __restrict__ x,
    const float* __restrict__ Wl,
    const float* __restrict__ Wr,
    float* __restrict__ hl,   // [N_NODES][HL_STRIDE], first 5 valid
    float* __restrict__ hr)   // [N_NODES][5]
{
    int node = (blockIdx.x * 256 + threadIdx.x) >> 4;
    int k    = threadIdx.x & 15;
    if (node >= N_NODES) return;

    const float4* xr = (const float4*)(x + (size_t)node * D_IN + k * 8);
    float4 x0 = xr[0];
    float4 x1 = xr[1];

    float s[10];
#pragma unroll
    for (int o = 0; o < 10; ++o) {
        const float* w = (o < 5 ? Wl + o * D_IN : Wr + (o - 5) * D_IN) + k * 8;
        float4 w0 = ((const float4*)w)[0];
        float4 w1 = ((const float4*)w)[1];
        s[o] = x0.x * w0.x + x0.y * w0.y + x0.z * w0.z + x0.w * w0.w
             + x1.x * w1.x + x1.y * w1.y + x1.z * w1.z + x1.w * w1.w;
    }

#pragma unroll
    for (int o = 0; o < 10; ++o) {
        s[o] += __shfl_xor(s[o], 8, 64);
        s[o] += __shfl_xor(s[o], 4, 64);
        s[o] += __shfl_xor(s[o], 2, 64);
        s[o] += __shfl_xor(s[o], 1, 64);
    }

    if (k == 0) {
        float* pl = hl + (size_t)node * HL_STRIDE;
        pl[0] = s[0]; pl[1] = s[1]; pl[2] = s[2]; pl[3] = s[3]; pl[4] = s[4];
        float* pr = hr + (size_t)node * 5;
        pr[0] = s[5]; pr[1] = s[6]; pr[2] = s[7]; pr[3] = s[8]; pr[4] = s[9];
    }
}

// ---------------------------------------------------------------------------
// Kernel 2: bucketed aggregation, zero global atomics.
// Grid = N_BUCKETS * N_CHUNKS. Block (bucket b, chunk c): stream chunk c's
// dst[] with int4 loads; edges with dst in bucket b accumulate h_l[src] + 1.0
// into the 2048x6 LDS accumulator (ds_add_f32, low contention); then flush
// the whole bucket to partials[c] with coalesced float4 stores.
// ---------------------------------------------------------------------------
__global__ __launch_bounds__(256) void bucket_kernel(
    const int* __restrict__ ei,       // [2][N_EDGES]: row0 src, row1 dst
    const float* __restrict__ hl,
    float* __restrict__ partials)     // [N_CHUNKS][NODES_PAD][6]
{
    __shared__ float acc[B_NODES * 6];   // 48 KB

    const int bucket = blockIdx.x % N_BUCKETS;
    const int chunk  = blockIdx.x / N_BUCKETS;
    const int base   = bucket * B_NODES;

    for (int i = threadIdx.x; i < B_NODES * 6 / 4; i += 256)
        ((float4*)acc)[i] = make_float4(0.f, 0.f, 0.f, 0.f);
    __syncthreads();

    const int e0 = chunk * CHUNK_E;
    const int* __restrict__ srcA = ei;
    const int4* __restrict__ dstv = (const int4*)(ei + N_EDGES + e0);

    for (int it = threadIdx.x; it < CHUNK_E / 4; it += 256) {
        int4 d = dstv[it];
        int e = e0 + it * 4;
#pragma unroll
        for (int q = 0; q < 4; ++q) {
            int dd = (q == 0) ? d.x : (q == 1) ? d.y : (q == 2) ? d.z : d.w;
            unsigned r = (unsigned)(dd - base);
            if (r < B_NODES) {
                int src = srcA[e + q];
                const float* p = hl + (size_t)src * HL_STRIDE;
                float4 v  = ((const float4*)p)[0];
                float  v4 = p[4];
                float* a = acc + r * 6;
                atomicAdd(a + 0, v.x);
                atomicAdd(a + 1, v.y);
                atomicAdd(a + 2, v.z);
                atomicAdd(a + 3, v.w);
                atomicAdd(a + 4, v4);
                atomicAdd(a + 5, 1.0f);
            }
        }
    }
    __syncthreads();

    // flush: 12288 floats = 3072 float4, coalesced
    float4* dst = (float4*)(partials + ((size_t)chunk * NODES_PAD + base) * 6);
    const float4* a4 = (const float4*)acc;
    for (int i = threadIdx.x; i < B_NODES * 6 / 4; i += 256)
        dst[i] = a4[i];
}

// ---------------------------------------------------------------------------
// Kernel 3: finalize. out[i] = (sum_c partials[c][i][0..4]) / max(deg,1)
//                              + b_l + hr[i]
// ---------------------------------------------------------------------------
__global__ __launch_bounds__(256) void final_kernel(
    const float* __restrict__ partials,
    const float* __restrict__ hr,
    const float* __restrict__ b,
    float* __restrict__ out)
{
    int i = blockIdx.x * 256 + threadIdx.x;
    if (i >= N_NODES) return;

    float s[6] = {0.f, 0.f, 0.f, 0.f, 0.f, 0.f};
#pragma unroll
    for (int c = 0; c < N_CHUNKS; ++c) {
        const float* p = partials + ((size_t)c * NODES_PAD + i) * 6;
#pragma unroll
        for (int ch = 0; ch < 6; ++ch) s[ch] += p[ch];
    }
    float rec = 1.0f / fmaxf(s[5], 1.0f);

    const float* h = hr + (size_t)i * 5;
    float* o = out + (size_t)i * 5;
#pragma unroll
    for (int c = 0; c < 5; ++c)
        o[c] = s[c] * rec + b[c] + h[c];
}

extern "C" void kernel_launch(void* const* d_in, const int* in_sizes, int n_in,
                              void* d_out, int out_size, void* d_ws, size_t ws_size,
                              hipStream_t stream) {
    const float* x    = (const float*)d_in[0];
    const int*   ei   = (const int*)d_in[1];
    const float* Wl   = (const float*)d_in[2];
    const float* bl   = (const float*)d_in[3];
    const float* Wr   = (const float*)d_in[4];
    float*       out  = (float*)d_out;

    // workspace layout (16B-aligned)
    float* hl       = (float*)d_ws;                          // 800000 f  (3.2 MB)
    float* hr       = hl + (size_t)N_NODES * HL_STRIDE;      // 500000 f  (2.0 MB)
    float* partials = hr + (size_t)N_NODES * 5;              // 8*100352*6 f (19.3 MB)

    {   // projection: 16 threads/node
        int blocks = (N_NODES * 16 + 255) / 256;             // 6250
        proj_kernel<<<blocks, 256, 0, stream>>>(x, Wl, Wr, hl, hr);
    }
    {   // bucketed aggregation: 49 buckets x 8 chunks
        bucket_kernel<<<N_BUCKETS * N_CHUNKS, 256, 0, stream>>>(ei, hl, partials);
    }
    {   // finalize
        int blocks = (N_NODES + 255) / 256;                  // 391
        final_kernel<<<blocks, 256, 0, stream>>>(partials, hr, bl, out);
    }
}

// Round 3
// 200.231 us; speedup vs baseline: 2.9586x; 2.3401x over previous
//
#include <hip/hip_runtime.h>
#include <hip/hip_bf16.h>

// SAGEConv mean-aggr: out_i = mean_{j->i} x_j @ W_l^T + b_l + x_i @ W_r^T
//
// R1 lesson: device-scope fp32 atomics = 32B write-through each -> 300 MB, 481 us.
// R2 lesson: bucket-scan without binning re-reads dst 49x, latency-bound at
//            17% occupancy -> 365 us.
// R3: counting-sort edges by dst-bucket ONCE (packed 4B records, per-block LDS
//     histogram + one global range-reservation per (block,bucket)), then each
//     aggregation block reads only its own contiguous edges and writes final
//     output directly. No partials, no redundant scan, no global fp32 atomics.

#define N_NODES 100000
#define N_EDGES 1600000
#define D_IN 128
#define D_OUT 5

#define HL_STRIDE 8

#define BSHIFT 9
#define B_NODES 512                    // nodes per bucket = 1<<BSHIFT
#define N_BUCKETS 196                  // ceil(100000/512)
#define CAP 10240                      // slots/bucket (mean 8192, sigma ~90)

#define SC_EPT 8                       // edges per scatter thread
#define SC_EPB (256 * SC_EPT)          // 2048 edges per scatter block
#define SC_GRID ((N_EDGES + SC_EPB - 1) / SC_EPB)   // 782

// ---------------------------------------------------------------------------
// Kernel 1: projection. 16 lanes/node, lane k covers dims [8k,8k+8).
// ---------------------------------------------------------------------------
__global__ __launch_bounds__(256) void proj_kernel(
    const float* __restrict__ x,
    const float* __restrict__ Wl,
    const float* __restrict__ Wr,
    float* __restrict__ hl,   // [N_NODES][HL_STRIDE], first 5 valid
    float* __restrict__ hr)   // [N_NODES][5]
{
    int node = (blockIdx.x * 256 + threadIdx.x) >> 4;
    int k    = threadIdx.x & 15;
    if (node >= N_NODES) return;

    const float4* xr = (const float4*)(x + (size_t)node * D_IN + k * 8);
    float4 x0 = xr[0];
    float4 x1 = xr[1];

    float s[10];
#pragma unroll
    for (int o = 0; o < 10; ++o) {
        const float* w = (o < 5 ? Wl + o * D_IN : Wr + (o - 5) * D_IN) + k * 8;
        float4 w0 = ((const float4*)w)[0];
        float4 w1 = ((const float4*)w)[1];
        s[o] = x0.x * w0.x + x0.y * w0.y + x0.z * w0.z + x0.w * w0.w
             + x1.x * w1.x + x1.y * w1.y + x1.z * w1.z + x1.w * w1.w;
    }

#pragma unroll
    for (int o = 0; o < 10; ++o) {
        s[o] += __shfl_xor(s[o], 8, 64);
        s[o] += __shfl_xor(s[o], 4, 64);
        s[o] += __shfl_xor(s[o], 2, 64);
        s[o] += __shfl_xor(s[o], 1, 64);
    }

    if (k == 0) {
        float* pl = hl + (size_t)node * HL_STRIDE;
        pl[0] = s[0]; pl[1] = s[1]; pl[2] = s[2]; pl[3] = s[3]; pl[4] = s[4];
        float* pr = hr + (size_t)node * 5;
        pr[0] = s[5]; pr[1] = s[6]; pr[2] = s[7]; pr[3] = s[8]; pr[4] = s[9];
    }
}

// ---------------------------------------------------------------------------
// Kernel 2: counting-sort scatter. Block handles 2048 edges:
//   pass 1: LDS hist over 196 buckets, per-edge slot via LDS atomicAdd
//   reserve: one global atomicAdd per (block,bucket) -> contiguous range
//   pass 2: write packed record (r<<17 | src) to sorted[bucket*CAP + base+slot]
// ---------------------------------------------------------------------------
__global__ __launch_bounds__(256) void scatter_kernel(
    const int* __restrict__ ei,         // [2][N_EDGES]: row0 src, row1 dst
    unsigned int* __restrict__ sorted,  // [N_BUCKETS][CAP]
    int* __restrict__ cursor)           // [N_BUCKETS], zero-initialized
{
    __shared__ int hist[N_BUCKETS];
    __shared__ int basepos[N_BUCKETS];

    const int tid = threadIdx.x;
    for (int i = tid; i < N_BUCKETS; i += 256) hist[i] = 0;
    __syncthreads();

    const int e0 = blockIdx.x * SC_EPB + tid * SC_EPT;

    int srcv[SC_EPT], dstv[SC_EPT], slot[SC_EPT];
    bool valid[SC_EPT];

    if (e0 + SC_EPT <= N_EDGES) {
        const int4* s4 = (const int4*)(ei + e0);
        const int4* d4 = (const int4*)(ei + N_EDGES + e0);
        int4 sa = s4[0], sb = s4[1], da = d4[0], db = d4[1];
        srcv[0]=sa.x; srcv[1]=sa.y; srcv[2]=sa.z; srcv[3]=sa.w;
        srcv[4]=sb.x; srcv[5]=sb.y; srcv[6]=sb.z; srcv[7]=sb.w;
        dstv[0]=da.x; dstv[1]=da.y; dstv[2]=da.z; dstv[3]=da.w;
        dstv[4]=db.x; dstv[5]=db.y; dstv[6]=db.z; dstv[7]=db.w;
#pragma unroll
        for (int q = 0; q < SC_EPT; ++q) valid[q] = true;
    } else {
#pragma unroll
        for (int q = 0; q < SC_EPT; ++q) {
            int e = e0 + q;
            valid[q] = (e < N_EDGES);
            srcv[q] = valid[q] ? ei[e] : 0;
            dstv[q] = valid[q] ? ei[N_EDGES + e] : 0;
        }
    }

#pragma unroll
    for (int q = 0; q < SC_EPT; ++q) {
        if (valid[q]) {
            int b = dstv[q] >> BSHIFT;
            slot[q] = atomicAdd(&hist[b], 1);
        }
    }
    __syncthreads();

    // reserve a contiguous global range per non-empty bucket
    for (int b = tid; b < N_BUCKETS; b += 256) {
        int c = hist[b];
        if (c > 0) basepos[b] = atomicAdd(&cursor[b], c);
    }
    __syncthreads();

#pragma unroll
    for (int q = 0; q < SC_EPT; ++q) {
        if (valid[q]) {
            int b = dstv[q] >> BSHIFT;
            int r = dstv[q] & (B_NODES - 1);
            unsigned int rec = ((unsigned int)r << 17) | (unsigned int)srcv[q];
            sorted[(size_t)b * CAP + basepos[b] + slot[q]] = rec;
        }
    }
}

// ---------------------------------------------------------------------------
// Kernel 3: per-bucket aggregation + finalize (fused). Block b reads only its
// own contiguous edge list, LDS-accumulates (512x6), writes final output.
// ---------------------------------------------------------------------------
__global__ __launch_bounds__(1024) void agg_kernel(
    const unsigned int* __restrict__ sorted,
    const int* __restrict__ cursor,
    const float* __restrict__ hl,
    const float* __restrict__ hr,
    const float* __restrict__ bias,
    float* __restrict__ out)
{
    __shared__ float acc[B_NODES * 6];   // 12 KB

    const int b   = blockIdx.x;
    const int tid = threadIdx.x;

    for (int i = tid; i < B_NODES * 6; i += 1024) acc[i] = 0.f;
    __syncthreads();

    const int cnt = cursor[b];
    const unsigned int* sp = sorted + (size_t)b * CAP;

    for (int i = tid; i < cnt; i += 1024) {
        unsigned int v = sp[i];
        int src = (int)(v & 0x1FFFFu);
        int r   = (int)(v >> 17);
        const float* p = hl + (size_t)src * HL_STRIDE;
        float4 h4 = *(const float4*)p;
        float  h5 = p[4];
        float* a = acc + r * 6;
        atomicAdd(a + 0, h4.x);
        atomicAdd(a + 1, h4.y);
        atomicAdd(a + 2, h4.z);
        atomicAdd(a + 3, h4.w);
        atomicAdd(a + 4, h5);
        atomicAdd(a + 5, 1.0f);
    }
    __syncthreads();

    const int nodebase = b << BSHIFT;
    for (int n = tid; n < B_NODES; n += 1024) {
        int node = nodebase + n;
        if (node >= N_NODES) continue;
        float deg = acc[n * 6 + 5];
        float rec = 1.0f / fmaxf(deg, 1.0f);
        const float* h = hr + (size_t)node * 5;
        float* o = out + (size_t)node * 5;
#pragma unroll
        for (int c = 0; c < 5; ++c)
            o[c] = acc[n * 6 + c] * rec + bias[c] + h[c];
    }
}

extern "C" void kernel_launch(void* const* d_in, const int* in_sizes, int n_in,
                              void* d_out, int out_size, void* d_ws, size_t ws_size,
                              hipStream_t stream) {
    const float* x    = (const float*)d_in[0];
    const int*   ei   = (const int*)d_in[1];
    const float* Wl   = (const float*)d_in[2];
    const float* bl   = (const float*)d_in[3];
    const float* Wr   = (const float*)d_in[4];
    float*       out  = (float*)d_out;

    // workspace layout (16B-aligned): total ~13.3 MB
    float*        hl     = (float*)d_ws;                         // 800000 f (3.2 MB)
    float*        hr     = hl + (size_t)N_NODES * HL_STRIDE;     // 500000 f (2.0 MB)
    unsigned int* sorted = (unsigned int*)(hr + (size_t)N_NODES * 5); // 196*10240 u32 (8.0 MB)
    int*          cursor = (int*)(sorted + (size_t)N_BUCKETS * CAP);  // 196 i32

    hipMemsetAsync(cursor, 0, N_BUCKETS * sizeof(int), stream);

    {   // projection: 16 threads/node
        int blocks = (N_NODES * 16 + 255) / 256;                 // 6250
        proj_kernel<<<blocks, 256, 0, stream>>>(x, Wl, Wr, hl, hr);
    }
    scatter_kernel<<<SC_GRID, 256, 0, stream>>>(ei, sorted, cursor);
    agg_kernel<<<N_BUCKETS, 1024, 0, stream>>>(sorted, cursor, hl, hr, bl, out);
}

// Round 4
// 196.162 us; speedup vs baseline: 3.0200x; 1.0207x over previous
//
#include <hip/hip_runtime.h>
#include <hip/hip_bf16.h>

// SAGEConv mean-aggr: out_i = mean_{j->i} x_j @ W_l^T + b_l + x_i @ W_r^T
//
// R1: global fp32 atomics write through L2 (32B each) -> 300 MB, 481 us. Dead end.
// R2: 49x redundant dst-scan, latency-bound at 17% occupancy -> 365 us.
// R3: counting-sort by dst-bucket + per-bucket LDS aggregation -> 200 us total,
//     but agg was 68 us with ALL pipes idle: 196 blocks < 256 CUs, MLP=1
//     (scalar record load -> dependent gather), possibly CAS-looped LDS atomics.
// R4: (a) 392 buckets x 256 nodes, 1024 thr -> full CU coverage, 2x waves;
//     (b) uint4 record loads + batched gathers -> MLP 4x;
//     (c) unsafeAtomicAdd on LDS (native ds_add_f32);
//     (d) proj+scatter fused into ONE dispatch (independent work, overlaps).

#define N_NODES 100000
#define N_EDGES 1600000
#define D_IN 128
#define D_OUT 5

#define HL_STRIDE 8

#define BSHIFT 8
#define B_NODES 256                    // nodes per bucket = 1<<BSHIFT
#define N_BUCKETS 392                  // ceil(100000/256)
#define CAP 5120                       // slots/bucket (mean 4096, sigma ~64)

#define SC_EPT 8                       // edges per scatter thread
#define SC_EPB (256 * SC_EPT)          // 2048 edges per scatter block
#define SC_GRID ((N_EDGES + SC_EPB - 1) / SC_EPB)   // 782

#define PROJ_BLOCKS ((N_NODES * 16 + 255) / 256)    // 6250
#define FUSED_GRID (PROJ_BLOCKS + SC_GRID)          // 7032

// ---------------------------------------------------------------------------
// Fused kernel A: blocks [0, PROJ_BLOCKS) do the projection; blocks
// [PROJ_BLOCKS, FUSED_GRID) do the counting-sort scatter. Independent work,
// one dispatch, runs concurrently across CUs.
// ---------------------------------------------------------------------------
__global__ __launch_bounds__(256) void proj_scatter_kernel(
    const float* __restrict__ x,
    const float* __restrict__ Wl,
    const float* __restrict__ Wr,
    float* __restrict__ hl,             // [N_NODES][HL_STRIDE], first 5 valid
    float* __restrict__ hr,             // [N_NODES][5]
    const int* __restrict__ ei,         // [2][N_EDGES]: row0 src, row1 dst
    unsigned int* __restrict__ sorted,  // [N_BUCKETS][CAP]
    int* __restrict__ cursor)           // [N_BUCKETS], zero-initialized
{
    if (blockIdx.x < PROJ_BLOCKS) {
        // ---------------- projection: 16 lanes/node ----------------
        int node = (blockIdx.x * 256 + threadIdx.x) >> 4;
        int k    = threadIdx.x & 15;
        if (node >= N_NODES) return;

        const float4* xr = (const float4*)(x + (size_t)node * D_IN + k * 8);
        float4 x0 = xr[0];
        float4 x1 = xr[1];

        float s[10];
#pragma unroll
        for (int o = 0; o < 10; ++o) {
            const float* w = (o < 5 ? Wl + o * D_IN : Wr + (o - 5) * D_IN) + k * 8;
            float4 w0 = ((const float4*)w)[0];
            float4 w1 = ((const float4*)w)[1];
            s[o] = x0.x * w0.x + x0.y * w0.y + x0.z * w0.z + x0.w * w0.w
                 + x1.x * w1.x + x1.y * w1.y + x1.z * w1.z + x1.w * w1.w;
        }

#pragma unroll
        for (int o = 0; o < 10; ++o) {
            s[o] += __shfl_xor(s[o], 8, 64);
            s[o] += __shfl_xor(s[o], 4, 64);
            s[o] += __shfl_xor(s[o], 2, 64);
            s[o] += __shfl_xor(s[o], 1, 64);
        }

        if (k == 0) {
            float* pl = hl + (size_t)node * HL_STRIDE;
            pl[0] = s[0]; pl[1] = s[1]; pl[2] = s[2]; pl[3] = s[3]; pl[4] = s[4];
            float* pr = hr + (size_t)node * 5;
            pr[0] = s[5]; pr[1] = s[6]; pr[2] = s[7]; pr[3] = s[8]; pr[4] = s[9];
        }
    } else {
        // ---------------- counting-sort scatter ----------------
        __shared__ int hist[N_BUCKETS];
        __shared__ int basepos[N_BUCKETS];

        const int tid = threadIdx.x;
        for (int i = tid; i < N_BUCKETS; i += 256) hist[i] = 0;
        __syncthreads();

        const int blk = blockIdx.x - PROJ_BLOCKS;
        const int e0  = blk * SC_EPB + tid * SC_EPT;

        int srcv[SC_EPT], dstv[SC_EPT], slot[SC_EPT];
        bool valid[SC_EPT];

        if (e0 + SC_EPT <= N_EDGES) {
            const int4* s4 = (const int4*)(ei + e0);
            const int4* d4 = (const int4*)(ei + N_EDGES + e0);
            int4 sa = s4[0], sb = s4[1], da = d4[0], db = d4[1];
            srcv[0]=sa.x; srcv[1]=sa.y; srcv[2]=sa.z; srcv[3]=sa.w;
            srcv[4]=sb.x; srcv[5]=sb.y; srcv[6]=sb.z; srcv[7]=sb.w;
            dstv[0]=da.x; dstv[1]=da.y; dstv[2]=da.z; dstv[3]=da.w;
            dstv[4]=db.x; dstv[5]=db.y; dstv[6]=db.z; dstv[7]=db.w;
#pragma unroll
            for (int q = 0; q < SC_EPT; ++q) valid[q] = true;
        } else {
#pragma unroll
            for (int q = 0; q < SC_EPT; ++q) {
                int e = e0 + q;
                valid[q] = (e < N_EDGES);
                srcv[q] = valid[q] ? ei[e] : 0;
                dstv[q] = valid[q] ? ei[N_EDGES + e] : 0;
            }
        }

#pragma unroll
        for (int q = 0; q < SC_EPT; ++q) {
            if (valid[q]) {
                int b = dstv[q] >> BSHIFT;
                slot[q] = atomicAdd(&hist[b], 1);
            }
        }
        __syncthreads();

        for (int b = tid; b < N_BUCKETS; b += 256) {
            int c = hist[b];
            if (c > 0) basepos[b] = atomicAdd(&cursor[b], c);
        }
        __syncthreads();

#pragma unroll
        for (int q = 0; q < SC_EPT; ++q) {
            if (valid[q]) {
                int b = dstv[q] >> BSHIFT;
                int r = dstv[q] & (B_NODES - 1);
                unsigned int rec = ((unsigned int)r << 17) | (unsigned int)srcv[q];
                sorted[(size_t)b * CAP + basepos[b] + slot[q]] = rec;
            }
        }
    }
}

// ---------------------------------------------------------------------------
// Kernel B: per-bucket aggregation + finalize. 392 blocks x 1024 threads.
// uint4 record loads (4 edges/iter), gathers batched before use (MLP=4),
// native LDS fp atomics, direct output write.
// ---------------------------------------------------------------------------
__global__ __launch_bounds__(1024) void agg_kernel(
    const unsigned int* __restrict__ sorted,
    const int* __restrict__ cursor,
    const float* __restrict__ hl,
    const float* __restrict__ hr,
    const float* __restrict__ bias,
    float* __restrict__ out)
{
    __shared__ float acc[B_NODES * 6];   // 6 KB

    const int b   = blockIdx.x;
    const int tid = threadIdx.x;

    for (int i = tid; i < B_NODES * 6; i += 1024) acc[i] = 0.f;
    __syncthreads();

    const int cnt = cursor[b];
    const unsigned int* sp = sorted + (size_t)b * CAP;
    const int nvec = cnt >> 2;

    for (int it = tid; it < nvec; it += 1024) {
        uint4 v = ((const uint4*)sp)[it];
        int s0 = (int)(v.x & 0x1FFFFu), r0 = (int)(v.x >> 17);
        int s1 = (int)(v.y & 0x1FFFFu), r1 = (int)(v.y >> 17);
        int s2 = (int)(v.z & 0x1FFFFu), r2 = (int)(v.z >> 17);
        int s3 = (int)(v.w & 0x1FFFFu), r3 = (int)(v.w >> 17);

        const float* p0 = hl + (size_t)s0 * HL_STRIDE;
        const float* p1 = hl + (size_t)s1 * HL_STRIDE;
        const float* p2 = hl + (size_t)s2 * HL_STRIDE;
        const float* p3 = hl + (size_t)s3 * HL_STRIDE;
        float4 h0 = *(const float4*)p0; float e0 = p0[4];
        float4 h1 = *(const float4*)p1; float e1 = p1[4];
        float4 h2 = *(const float4*)p2; float e2 = p2[4];
        float4 h3 = *(const float4*)p3; float e3 = p3[4];

        float* a0 = acc + r0 * 6;
        float* a1 = acc + r1 * 6;
        float* a2 = acc + r2 * 6;
        float* a3 = acc + r3 * 6;
        unsafeAtomicAdd(a0 + 0, h0.x); unsafeAtomicAdd(a0 + 1, h0.y);
        unsafeAtomicAdd(a0 + 2, h0.z); unsafeAtomicAdd(a0 + 3, h0.w);
        unsafeAtomicAdd(a0 + 4, e0);   unsafeAtomicAdd(a0 + 5, 1.0f);
        unsafeAtomicAdd(a1 + 0, h1.x); unsafeAtomicAdd(a1 + 1, h1.y);
        unsafeAtomicAdd(a1 + 2, h1.z); unsafeAtomicAdd(a1 + 3, h1.w);
        unsafeAtomicAdd(a1 + 4, e1);   unsafeAtomicAdd(a1 + 5, 1.0f);
        unsafeAtomicAdd(a2 + 0, h2.x); unsafeAtomicAdd(a2 + 1, h2.y);
        unsafeAtomicAdd(a2 + 2, h2.z); unsafeAtomicAdd(a2 + 3, h2.w);
        unsafeAtomicAdd(a2 + 4, e2);   unsafeAtomicAdd(a2 + 5, 1.0f);
        unsafeAtomicAdd(a3 + 0, h3.x); unsafeAtomicAdd(a3 + 1, h3.y);
        unsafeAtomicAdd(a3 + 2, h3.z); unsafeAtomicAdd(a3 + 3, h3.w);
        unsafeAtomicAdd(a3 + 4, e3);   unsafeAtomicAdd(a3 + 5, 1.0f);
    }
    // tail (<4 records)
    for (int i = (nvec << 2) + tid; i < cnt; i += 1024) {
        unsigned int v = sp[i];
        int src = (int)(v & 0x1FFFFu);
        int r   = (int)(v >> 17);
        const float* p = hl + (size_t)src * HL_STRIDE;
        float4 h4 = *(const float4*)p;
        float  h5 = p[4];
        float* a = acc + r * 6;
        unsafeAtomicAdd(a + 0, h4.x); unsafeAtomicAdd(a + 1, h4.y);
        unsafeAtomicAdd(a + 2, h4.z); unsafeAtomicAdd(a + 3, h4.w);
        unsafeAtomicAdd(a + 4, h5);   unsafeAtomicAdd(a + 5, 1.0f);
    }
    __syncthreads();

    const int nodebase = b << BSHIFT;
    for (int n = tid; n < B_NODES; n += 1024) {
        int node = nodebase + n;
        if (node >= N_NODES) continue;
        float deg = acc[n * 6 + 5];
        float rec = 1.0f / fmaxf(deg, 1.0f);
        const float* h = hr + (size_t)node * 5;
        float* o = out + (size_t)node * 5;
#pragma unroll
        for (int c = 0; c < 5; ++c)
            o[c] = acc[n * 6 + c] * rec + bias[c] + h[c];
    }
}

extern "C" void kernel_launch(void* const* d_in, const int* in_sizes, int n_in,
                              void* d_out, int out_size, void* d_ws, size_t ws_size,
                              hipStream_t stream) {
    const float* x    = (const float*)d_in[0];
    const int*   ei   = (const int*)d_in[1];
    const float* Wl   = (const float*)d_in[2];
    const float* bl   = (const float*)d_in[3];
    const float* Wr   = (const float*)d_in[4];
    float*       out  = (float*)d_out;

    // workspace layout (16B-aligned): ~13.3 MB total
    float*        hl     = (float*)d_ws;                              // 800000 f
    float*        hr     = hl + (size_t)N_NODES * HL_STRIDE;          // 500000 f
    unsigned int* sorted = (unsigned int*)(hr + (size_t)N_NODES * 5); // 392*5120 u32
    int*          cursor = (int*)(sorted + (size_t)N_BUCKETS * CAP);  // 392 i32

    hipMemsetAsync(cursor, 0, N_BUCKETS * sizeof(int), stream);

    proj_scatter_kernel<<<FUSED_GRID, 256, 0, stream>>>(
        x, Wl, Wr, hl, hr, ei, sorted, cursor);

    agg_kernel<<<N_BUCKETS, 1024, 0, stream>>>(sorted, cursor, hl, hr, bl, out);
}

// Round 5
// 141.746 us; speedup vs baseline: 4.1793x; 1.3839x over previous
//
#include <hip/hip_runtime.h>
#include <hip/hip_bf16.h>

// SAGEConv mean-aggr: out_i = mean_{j->i} x_j @ W_l^T + b_l + x_i @ W_r^T
//
// R1: global fp32 atomics write through L2 (32B each) -> 300 MB, 481 us.
// R2: 49x redundant dst-scan, latency-bound -> 365 us.
// R3: counting-sort by dst-bucket + per-bucket LDS fp-atomic agg -> 200 us.
// R4: occupancy x2 + MLP=4 + unsafeAtomicAdd: agg UNCHANGED (69.5 us, all
//     pipes idle). Theory: fp32 LDS atomicAdd lowers to a generic-pointer
//     CAS loop, not ds_add_f32 (SQ_LDS_BANK_CONFLICT==0 across R2-R4, and
//     atomic flavor made zero difference).
// R5: integer fixed-point accumulation -> 3 native ds_add_u64 per edge
//     (two biased u32 fields per u64; SCALE=2^18, BIAS=2^24; deg<=64 keeps
//     field sums < 2^31). proj_scatter untouched (single-variable change).

#define N_NODES 100000
#define N_EDGES 1600000
#define D_IN 128
#define D_OUT 5

#define HL_STRIDE 8

#define BSHIFT 8
#define B_NODES 256                    // nodes per bucket = 1<<BSHIFT
#define N_BUCKETS 392                  // ceil(100000/256)
#define CAP 5120                       // slots/bucket (mean 4096, sigma ~64)

#define SC_EPT 8                       // edges per scatter thread
#define SC_EPB (256 * SC_EPT)          // 2048 edges per scatter block
#define SC_GRID ((N_EDGES + SC_EPB - 1) / SC_EPB)   // 782

#define PROJ_BLOCKS ((N_NODES * 16 + 255) / 256)    // 6250
#define FUSED_GRID (PROJ_BLOCKS + SC_GRID)          // 7032

// fixed-point params for integer LDS accumulation
#define FXS 262144.0f                  // 2^18 scale
#define FXB 16777216u                  // 2^24 bias (per addend)
#define FXBF 16777216.0f
#define INV_FXS (1.0f / 262144.0f)

typedef unsigned long long u64;
typedef unsigned int u32;

// ---------------------------------------------------------------------------
// Fused kernel A: blocks [0, PROJ_BLOCKS) projection; rest counting-sort
// scatter. Identical to R4.
// ---------------------------------------------------------------------------
__global__ __launch_bounds__(256) void proj_scatter_kernel(
    const float* __restrict__ x,
    const float* __restrict__ Wl,
    const float* __restrict__ Wr,
    float* __restrict__ hl,             // [N_NODES][HL_STRIDE], first 5 valid
    float* __restrict__ hr,             // [N_NODES][5]
    const int* __restrict__ ei,         // [2][N_EDGES]: row0 src, row1 dst
    unsigned int* __restrict__ sorted,  // [N_BUCKETS][CAP]
    int* __restrict__ cursor)           // [N_BUCKETS], zero-initialized
{
    if (blockIdx.x < PROJ_BLOCKS) {
        int node = (blockIdx.x * 256 + threadIdx.x) >> 4;
        int k    = threadIdx.x & 15;
        if (node >= N_NODES) return;

        const float4* xr = (const float4*)(x + (size_t)node * D_IN + k * 8);
        float4 x0 = xr[0];
        float4 x1 = xr[1];

        float s[10];
#pragma unroll
        for (int o = 0; o < 10; ++o) {
            const float* w = (o < 5 ? Wl + o * D_IN : Wr + (o - 5) * D_IN) + k * 8;
            float4 w0 = ((const float4*)w)[0];
            float4 w1 = ((const float4*)w)[1];
            s[o] = x0.x * w0.x + x0.y * w0.y + x0.z * w0.z + x0.w * w0.w
                 + x1.x * w1.x + x1.y * w1.y + x1.z * w1.z + x1.w * w1.w;
        }

#pragma unroll
        for (int o = 0; o < 10; ++o) {
            s[o] += __shfl_xor(s[o], 8, 64);
            s[o] += __shfl_xor(s[o], 4, 64);
            s[o] += __shfl_xor(s[o], 2, 64);
            s[o] += __shfl_xor(s[o], 1, 64);
        }

        if (k == 0) {
            float* pl = hl + (size_t)node * HL_STRIDE;
            pl[0] = s[0]; pl[1] = s[1]; pl[2] = s[2]; pl[3] = s[3]; pl[4] = s[4];
            float* pr = hr + (size_t)node * 5;
            pr[0] = s[5]; pr[1] = s[6]; pr[2] = s[7]; pr[3] = s[8]; pr[4] = s[9];
        }
    } else {
        __shared__ int hist[N_BUCKETS];
        __shared__ int basepos[N_BUCKETS];

        const int tid = threadIdx.x;
        for (int i = tid; i < N_BUCKETS; i += 256) hist[i] = 0;
        __syncthreads();

        const int blk = blockIdx.x - PROJ_BLOCKS;
        const int e0  = blk * SC_EPB + tid * SC_EPT;

        int srcv[SC_EPT], dstv[SC_EPT], slot[SC_EPT];
        bool valid[SC_EPT];

        if (e0 + SC_EPT <= N_EDGES) {
            const int4* s4 = (const int4*)(ei + e0);
            const int4* d4 = (const int4*)(ei + N_EDGES + e0);
            int4 sa = s4[0], sb = s4[1], da = d4[0], db = d4[1];
            srcv[0]=sa.x; srcv[1]=sa.y; srcv[2]=sa.z; srcv[3]=sa.w;
            srcv[4]=sb.x; srcv[5]=sb.y; srcv[6]=sb.z; srcv[7]=sb.w;
            dstv[0]=da.x; dstv[1]=da.y; dstv[2]=da.z; dstv[3]=da.w;
            dstv[4]=db.x; dstv[5]=db.y; dstv[6]=db.z; dstv[7]=db.w;
#pragma unroll
            for (int q = 0; q < SC_EPT; ++q) valid[q] = true;
        } else {
#pragma unroll
            for (int q = 0; q < SC_EPT; ++q) {
                int e = e0 + q;
                valid[q] = (e < N_EDGES);
                srcv[q] = valid[q] ? ei[e] : 0;
                dstv[q] = valid[q] ? ei[N_EDGES + e] : 0;
            }
        }

#pragma unroll
        for (int q = 0; q < SC_EPT; ++q) {
            if (valid[q]) {
                int b = dstv[q] >> BSHIFT;
                slot[q] = atomicAdd(&hist[b], 1);
            }
        }
        __syncthreads();

        for (int b = tid; b < N_BUCKETS; b += 256) {
            int c = hist[b];
            if (c > 0) basepos[b] = atomicAdd(&cursor[b], c);
        }
        __syncthreads();

#pragma unroll
        for (int q = 0; q < SC_EPT; ++q) {
            if (valid[q]) {
                int b = dstv[q] >> BSHIFT;
                int r = dstv[q] & (B_NODES - 1);
                unsigned int rec = ((unsigned int)r << 17) | (unsigned int)srcv[q];
                sorted[(size_t)b * CAP + basepos[b] + slot[q]] = rec;
            }
        }
    }
}

// ---------------------------------------------------------------------------
// Kernel B: per-bucket aggregation via NATIVE integer LDS atomics.
// Each edge: gather h_l[src] (5 floats), convert to biased fixed-point
// (f*2^18 + 2^24, always positive), pack into 3 u64 words:
//   w0 = [ch1|ch0]  w1 = [ch3|ch2]  w2 = [ch4|deg]
// and ds_add_u64 each. Field sums stay < 2^31 (deg <= ~64), so no carry
// crosses the 32-bit field boundary. Finalize: ch = (field - deg*BIAS)/2^18.
// ---------------------------------------------------------------------------
__global__ __launch_bounds__(1024) void agg_kernel(
    const unsigned int* __restrict__ sorted,
    const int* __restrict__ cursor,
    const float* __restrict__ hl,
    const float* __restrict__ hr,
    const float* __restrict__ bias,
    float* __restrict__ out)
{
    __shared__ u64 acc[B_NODES * 3];   // 6 KB

    const int b   = blockIdx.x;
    const int tid = threadIdx.x;

    for (int i = tid; i < B_NODES * 3; i += 1024) acc[i] = 0ull;
    __syncthreads();

    const int cnt = cursor[b];
    const unsigned int* sp = sorted + (size_t)b * CAP;
    const int nvec = cnt >> 2;

    for (int it = tid; it < nvec; it += 1024) {
        uint4 v = ((const uint4*)sp)[it];
        unsigned int rr[4] = { v.x, v.y, v.z, v.w };
#pragma unroll
        for (int q = 0; q < 4; ++q) {
            int src = (int)(rr[q] & 0x1FFFFu);
            int r   = (int)(rr[q] >> 17);
            const float* p = hl + (size_t)src * HL_STRIDE;
            float4 h = *(const float4*)p;
            float  e = p[4];
            u32 f0 = __float2uint_rn(fmaf(h.x, FXS, FXBF));
            u32 f1 = __float2uint_rn(fmaf(h.y, FXS, FXBF));
            u32 f2 = __float2uint_rn(fmaf(h.z, FXS, FXBF));
            u32 f3 = __float2uint_rn(fmaf(h.w, FXS, FXBF));
            u32 f4 = __float2uint_rn(fmaf(e,   FXS, FXBF));
            u64* a = acc + r * 3;
            atomicAdd(&a[0], ((u64)f1 << 32) | f0);
            atomicAdd(&a[1], ((u64)f3 << 32) | f2);
            atomicAdd(&a[2], ((u64)f4 << 32) | 1u);
        }
    }
    for (int i = (nvec << 2) + tid; i < cnt; i += 1024) {
        unsigned int v = sp[i];
        int src = (int)(v & 0x1FFFFu);
        int r   = (int)(v >> 17);
        const float* p = hl + (size_t)src * HL_STRIDE;
        float4 h = *(const float4*)p;
        float  e = p[4];
        u32 f0 = __float2uint_rn(fmaf(h.x, FXS, FXBF));
        u32 f1 = __float2uint_rn(fmaf(h.y, FXS, FXBF));
        u32 f2 = __float2uint_rn(fmaf(h.z, FXS, FXBF));
        u32 f3 = __float2uint_rn(fmaf(h.w, FXS, FXBF));
        u32 f4 = __float2uint_rn(fmaf(e,   FXS, FXBF));
        u64* a = acc + r * 3;
        atomicAdd(&a[0], ((u64)f1 << 32) | f0);
        atomicAdd(&a[1], ((u64)f3 << 32) | f2);
        atomicAdd(&a[2], ((u64)f4 << 32) | 1u);
    }
    __syncthreads();

    const int nodebase = b << BSHIFT;
    for (int n = tid; n < B_NODES; n += 1024) {
        int node = nodebase + n;
        if (node >= N_NODES) continue;
        u64 w0 = acc[n * 3 + 0];
        u64 w1 = acc[n * 3 + 1];
        u64 w2 = acc[n * 3 + 2];
        u32 deg = (u32)(w2 & 0xFFFFFFFFu);
        u32 db  = deg * FXB;            // wraparound-safe: true values fit i32
        int i0 = (int)((u32)(w0 & 0xFFFFFFFFu) - db);
        int i1 = (int)((u32)(w0 >> 32)         - db);
        int i2 = (int)((u32)(w1 & 0xFFFFFFFFu) - db);
        int i3 = (int)((u32)(w1 >> 32)         - db);
        int i4 = (int)((u32)(w2 >> 32)         - db);

        float rec = INV_FXS / fmaxf((float)deg, 1.0f);
        const float* h = hr + (size_t)node * 5;
        float* o = out + (size_t)node * 5;
        o[0] = (float)i0 * rec + bias[0] + h[0];
        o[1] = (float)i1 * rec + bias[1] + h[1];
        o[2] = (float)i2 * rec + bias[2] + h[2];
        o[3] = (float)i3 * rec + bias[3] + h[3];
        o[4] = (float)i4 * rec + bias[4] + h[4];
    }
}

extern "C" void kernel_launch(void* const* d_in, const int* in_sizes, int n_in,
                              void* d_out, int out_size, void* d_ws, size_t ws_size,
                              hipStream_t stream) {
    const float* x    = (const float*)d_in[0];
    const int*   ei   = (const int*)d_in[1];
    const float* Wl   = (const float*)d_in[2];
    const float* bl   = (const float*)d_in[3];
    const float* Wr   = (const float*)d_in[4];
    float*       out  = (float*)d_out;

    // workspace layout (16B-aligned): ~13.3 MB total
    float*        hl     = (float*)d_ws;                              // 800000 f
    float*        hr     = hl + (size_t)N_NODES * HL_STRIDE;          // 500000 f
    unsigned int* sorted = (unsigned int*)(hr + (size_t)N_NODES * 5); // 392*5120 u32
    int*          cursor = (int*)(sorted + (size_t)N_BUCKETS * CAP);  // 392 i32

    hipMemsetAsync(cursor, 0, N_BUCKETS * sizeof(int), stream);

    proj_scatter_kernel<<<FUSED_GRID, 256, 0, stream>>>(
        x, Wl, Wr, hl, hr, ei, sorted, cursor);

    agg_kernel<<<N_BUCKETS, 1024, 0, stream>>>(sorted, cursor, hl, hr, bl, out);
}